// Round 1
// baseline (54664.563 us; speedup 1.0000x reference)
//
#include <hip/hip_runtime.h>
#include <stdint.h>
#include <stddef.h>

#define BB 32
#define TT 64
#define DD 512
#define HH 8
#define HDIM 64
#define LL 4
#define FFD 2048
#define VV 128

// ---------------- threefry2x32 (20 rounds), matches JAX ----------------
__host__ __device__ inline uint32_t rotl32(uint32_t v, int n){ return (v << n) | (v >> (32 - n)); }

__host__ __device__ inline void tf2x32(uint32_t k0, uint32_t k1, uint32_t x0, uint32_t x1,
                                       uint32_t* o0, uint32_t* o1){
  uint32_t ks2 = k0 ^ k1 ^ 0x1BD11BDAu;
  x0 += k0; x1 += k1;
  x0 += x1; x1 = rotl32(x1,13); x1 ^= x0;
  x0 += x1; x1 = rotl32(x1,15); x1 ^= x0;
  x0 += x1; x1 = rotl32(x1,26); x1 ^= x0;
  x0 += x1; x1 = rotl32(x1, 6); x1 ^= x0;
  x0 += k1; x1 += ks2 + 1u;
  x0 += x1; x1 = rotl32(x1,17); x1 ^= x0;
  x0 += x1; x1 = rotl32(x1,29); x1 ^= x0;
  x0 += x1; x1 = rotl32(x1,16); x1 ^= x0;
  x0 += x1; x1 = rotl32(x1,24); x1 ^= x0;
  x0 += ks2; x1 += k0 + 2u;
  x0 += x1; x1 = rotl32(x1,13); x1 ^= x0;
  x0 += x1; x1 = rotl32(x1,15); x1 ^= x0;
  x0 += x1; x1 = rotl32(x1,26); x1 ^= x0;
  x0 += x1; x1 = rotl32(x1, 6); x1 ^= x0;
  x0 += k0; x1 += k1 + 3u;
  x0 += x1; x1 = rotl32(x1,17); x1 ^= x0;
  x0 += x1; x1 = rotl32(x1,29); x1 ^= x0;
  x0 += x1; x1 = rotl32(x1,16); x1 ^= x0;
  x0 += x1; x1 = rotl32(x1,24); x1 ^= x0;
  x0 += k1; x1 += ks2 + 4u;
  x0 += x1; x1 = rotl32(x1,13); x1 ^= x0;
  x0 += x1; x1 = rotl32(x1,15); x1 ^= x0;
  x0 += x1; x1 = rotl32(x1,26); x1 ^= x0;
  x0 += x1; x1 = rotl32(x1, 6); x1 ^= x0;
  x0 += ks2; x1 += k0 + 5u;
  *o0 = x0; *o1 = x1;
}

// ---------------- helpers ----------------
__device__ inline float dot_f4(const float* __restrict__ a, const float* __restrict__ w, int K){
  float acc = 0.f;
  const float4* a4 = (const float4*)a;
  const float4* w4 = (const float4*)w;
  int K4 = K >> 2;
  for (int k = 0; k < K4; ++k){
    float4 av = a4[k], wv = w4[k];
    acc = fmaf(av.x, wv.x, acc);
    acc = fmaf(av.y, wv.y, acc);
    acc = fmaf(av.z, wv.z, acc);
    acc = fmaf(av.w, wv.w, acc);
  }
  return acc;
}

// LayerNorm across a 512-thread block (one value per thread). red = __shared__ float[8].
__device__ inline float block_ln(float v, float g, float bb, float* red){
  __syncthreads();
  float s = v;
  #pragma unroll
  for (int off = 32; off; off >>= 1) s += __shfl_xor(s, off);
  if ((threadIdx.x & 63) == 0) red[threadIdx.x >> 6] = s;
  __syncthreads();
  float mu = (red[0]+red[1]+red[2]+red[3]+red[4]+red[5]+red[6]+red[7]) * (1.0f/512.0f);
  float dv = v - mu;
  float sq = dv * dv;
  #pragma unroll
  for (int off = 32; off; off >>= 1) sq += __shfl_xor(sq, off);
  __syncthreads();
  if ((threadIdx.x & 63) == 0) red[threadIdx.x >> 6] = sq;
  __syncthreads();
  float var = (red[0]+red[1]+red[2]+red[3]+red[4]+red[5]+red[6]+red[7]) * (1.0f/512.0f);
  return dv * (1.0f / sqrtf(var + 1e-5f)) * g + bb;
}

// ---------------- setup kernels ----------------
__global__ void k_tables(float* __restrict__ cosb, float* __restrict__ sinb){
  int tid = blockIdx.x * blockDim.x + threadIdx.x;  // TT*256
  int p = tid >> 8, i = tid & 255;
  float sv = (2.0f * (float)i + 204.8f) / 716.8f;
  float scale = powf(sv, (float)p / 16.0f);
  float invf = 1.0f / powf(10000.0f, (float)i / 256.0f);
  float ang = (float)p * invf;
  cosb[tid] = cosf(ang) * scale;
  sinb[tid] = sinf(ang) * scale;
}

// cross-attn v-projection: tmp[l,b,d] = mol[b,:] . ca_in_w[l, 2D+d, :] + ca_in_b[l, 2D+d]
__global__ void k_ca1(const float* __restrict__ mol, const float* __restrict__ w,
                      const float* __restrict__ bias, float* __restrict__ tmp){
  int tid = blockIdx.x * blockDim.x + threadIdx.x;  // LL*BB*DD
  int l = tid >> 14; int r = tid & 16383; int b = r >> 9; int d = r & 511;
  const float* wr = w + (size_t)l*3*DD*DD + (size_t)(2*DD + d)*DD;
  tmp[tid] = bias[l*3*DD + 2*DD + d] + dot_f4(mol + (size_t)b*DD, wr, DD);
}

// cross-attn out-projection: cac[l,b,d] = tmp[l,b,:] . ca_out_w[l,d,:] + ca_out_b[l,d]
__global__ void k_ca2(const float* __restrict__ tmp, const float* __restrict__ w,
                      const float* __restrict__ bias, float* __restrict__ cac){
  int tid = blockIdx.x * blockDim.x + threadIdx.x;  // LL*BB*DD
  int l = tid >> 14; int r = tid & 16383; int b = r >> 9; int d = r & 511;
  const float* wr = w + (size_t)l*DD*DD + (size_t)d*DD;
  cac[tid] = bias[l*DD + d] + dot_f4(tmp + ((size_t)l*BB + b)*DD, wr, DD);
}

__global__ void k_init(int* __restrict__ pred){
  int tid = blockIdx.x * blockDim.x + threadIdx.x;
  if (tid < BB*TT) pred[tid] = ((tid & (TT-1)) == 0) ? 1 : 0;
}

// ---------------- per-step kernels ----------------
// x[b,d] = xpos(emb[pred[b,p]], p)
__global__ void k_embed(const int* __restrict__ pred, const float* __restrict__ emb,
                        const float* __restrict__ cosb, const float* __restrict__ sinb,
                        float* __restrict__ x, int p){
  int tid = blockIdx.x * blockDim.x + threadIdx.x;  // BB*DD
  int b = tid >> 9, d = tid & 511;
  int tok = pred[b*TT + p];
  int i = d >> 1;
  float c = cosb[p*256 + i], s = sinb[p*256 + i];
  float e0 = emb[(size_t)tok*DD + (d & ~1)];
  float e1 = emb[(size_t)tok*DD + (d | 1)];
  x[tid] = (d & 1) ? fmaf(e1, c, e0*s) : fmaf(e0, c, -(e1*s));
}

// QKV projection; q -> qbuf, k/v -> caches at position p
__global__ void k_qkv(const float* __restrict__ x, const float* __restrict__ w,
                      const float* __restrict__ bias, float* __restrict__ q,
                      float* __restrict__ kc, float* __restrict__ vc, int l, int p){
  int tid = blockIdx.x * blockDim.x + threadIdx.x;  // BB*3DD
  int b = tid / (3*DD), n = tid % (3*DD);
  const float* wr = w + (size_t)l*3*DD*DD + (size_t)n*DD;
  float acc = bias[l*3*DD + n] + dot_f4(x + (size_t)b*DD, wr, DD);
  if (n < DD){
    q[b*DD + n] = acc;
  } else if (n < 2*DD){
    int h = (n - DD) >> 6, hd = (n - DD) & 63;
    kc[((((size_t)l*BB + b)*HH + h)*TT + p)*HDIM + hd] = acc;
  } else {
    int h = (n - 2*DD) >> 6, hd = (n - 2*DD) & 63;
    vc[((((size_t)l*BB + b)*HH + h)*TT + p)*HDIM + hd] = acc;
  }
}

// attention for one (b,h): 64 threads (one wave)
__global__ __launch_bounds__(64) void k_attn(const float* __restrict__ q,
    const float* __restrict__ kc, const float* __restrict__ vc,
    const int* __restrict__ pred, float* __restrict__ out, int l, int p){
  int bh = blockIdx.x; int b = bh >> 3, h = bh & 7;
  int lane = threadIdx.x;
  __shared__ float qs[HDIM];
  __shared__ float ps[TT];
  qs[lane] = q[b*DD + h*HDIM + lane];
  __syncthreads();
  const float* kbase = kc + (((size_t)l*BB + b)*HH + h)*TT*HDIM;
  float s = -INFINITY;
  if (lane <= p && pred[b*TT + lane] != 0){
    const float* kr = kbase + lane*HDIM;
    float acc = 0.f;
    #pragma unroll
    for (int k2 = 0; k2 < HDIM; ++k2) acc = fmaf(qs[k2], kr[k2], acc);
    s = acc * 0.125f;   // /sqrt(64), exact
  }
  float m = s;
  #pragma unroll
  for (int off = 32; off; off >>= 1) m = fmaxf(m, __shfl_xor(m, off));
  float e = (s == -INFINITY) ? 0.f : expf(s - m);
  float sum = e;
  #pragma unroll
  for (int off = 32; off; off >>= 1) sum += __shfl_xor(sum, off);
  ps[lane] = e / sum;
  __syncthreads();
  const float* vbase = vc + (((size_t)l*BB + b)*HH + h)*TT*HDIM;
  float o = 0.f;
  for (int j = 0; j <= p; ++j) o = fmaf(ps[j], vbase[j*HDIM + lane], o);
  out[b*DD + h*HDIM + lane] = o;
}

// attn out-proj + residual + LN1, then + cross-attn const + LN2
__global__ __launch_bounds__(512) void k_oproj_ln(
    const float* __restrict__ attn, const float* __restrict__ w, const float* __restrict__ bias,
    const float* __restrict__ cac,
    const float* __restrict__ g1, const float* __restrict__ b1,
    const float* __restrict__ g2, const float* __restrict__ b2,
    float* __restrict__ x, int l){
  __shared__ float red[8];
  int b = blockIdx.x, d = threadIdx.x;
  float a = bias[l*DD + d] + dot_f4(attn + (size_t)b*DD, w + ((size_t)l*DD + d)*DD, DD);
  float xv = x[b*DD + d] + a;
  xv = block_ln(xv, g1[l*DD + d], b1[l*DD + d], red);
  xv = xv + cac[((size_t)l*BB + b)*DD + d];
  xv = block_ln(xv, g2[l*DD + d], b2[l*DD + d], red);
  x[b*DD + d] = xv;
}

__global__ void k_ff1(const float* __restrict__ x, const float* __restrict__ w,
                      const float* __restrict__ bias, float* __restrict__ h1, int l){
  int tid = blockIdx.x * blockDim.x + threadIdx.x;  // BB*FFD
  int b = tid / FFD, n = tid % FFD;
  float acc = bias[l*FFD + n] + dot_f4(x + (size_t)b*DD, w + ((size_t)l*FFD + n)*DD, DD);
  h1[tid] = acc / (1.0f + expf(-acc));   // silu
}

// FF second matmul + residual + LN3; if last layer also final LN -> xf
__global__ __launch_bounds__(512) void k_ff2_ln(
    const float* __restrict__ h1, const float* __restrict__ w, const float* __restrict__ bias,
    const float* __restrict__ g3, const float* __restrict__ b3,
    const float* __restrict__ fg, const float* __restrict__ fb,
    float* __restrict__ x, float* __restrict__ xf, int l, int last){
  __shared__ float red[8];
  int b = blockIdx.x, d = threadIdx.x;
  float f = bias[l*DD + d] + dot_f4(h1 + (size_t)b*FFD, w + ((size_t)l*DD + d)*FFD, FFD);
  float xv = x[b*DD + d] + f;
  xv = block_ln(xv, g3[l*DD + d], b3[l*DD + d], red);
  x[b*DD + d] = xv;
  if (last){
    float o = block_ln(xv, fg[d], fb[d], red);
    xf[b*DD + d] = o;
  }
}

// generic head matmul + exact gelu
__global__ void k_head(const float* __restrict__ in, const float* __restrict__ w,
                       const float* __restrict__ bias, float* __restrict__ out, int N, int K){
  int tid = blockIdx.x * blockDim.x + threadIdx.x;  // BB*N
  int b = tid / N, n = tid % N;
  float acc = bias[n] + dot_f4(in + (size_t)b*K, w + (size_t)n*K, K);
  out[tid] = 0.5f * acc * (1.0f + erff(acc / 1.41421356237309504880f));
}

// logits + log_softmax + gumbel + argmax  (one block per batch row, 128 threads)
__global__ __launch_bounds__(128) void k_sample(const float* __restrict__ h2,
    const float* __restrict__ w3, const float* __restrict__ b3,
    int* __restrict__ pred, int t, uint32_t kk0, uint32_t kk1){
  int b = blockIdx.x, v = threadIdx.x;
  __shared__ float hrow[1024];
  __shared__ float red[2];
  __shared__ int   redi[2];
  for (int k = v; k < 1024; k += 128) hrow[k] = h2[b*1024 + k];
  __syncthreads();
  float acc = b3[v] + dot_f4(hrow, w3 + (size_t)v*1024, 1024);
  float s = acc / 0.1f;
  // block max (2 waves)
  float m = s;
  #pragma unroll
  for (int off = 32; off; off >>= 1) m = fmaxf(m, __shfl_xor(m, off));
  if ((v & 63) == 0) red[v >> 6] = m;
  __syncthreads();
  m = fmaxf(red[0], red[1]);
  float sh = s - m;
  float e = expf(sh);
  float sum = e;
  #pragma unroll
  for (int off = 32; off; off >>= 1) sum += __shfl_xor(sum, off);
  __syncthreads();
  if ((v & 63) == 0) red[v >> 6] = sum;
  __syncthreads();
  sum = red[0] + red[1];
  float lp = sh - logf(sum);
  // gumbel noise: partitionable threefry bits = o0 ^ o1 of tf(key, 0, flat_idx)
  uint32_t o0, o1;
  tf2x32(kk0, kk1, 0u, (uint32_t)(b*VV + v), &o0, &o1);
  uint32_t bits = o0 ^ o1;
  float u = __uint_as_float((bits >> 9) | 0x3F800000u) - 1.0f;
  float g = -logf(-logf(u + 1e-9f) + 1e-9f);
  float y = lp + g;
  // argmax, first-index tiebreak
  float bv = y; int bi = v;
  #pragma unroll
  for (int off = 32; off; off >>= 1){
    float ov = __shfl_xor(bv, off);
    int   oi = __shfl_xor(bi, off);
    if (ov > bv || (ov == bv && oi < bi)){ bv = ov; bi = oi; }
  }
  __syncthreads();
  if ((v & 63) == 0){ red[v >> 6] = bv; redi[v >> 6] = bi; }
  __syncthreads();
  if (v == 0){
    float v0 = red[0], v1 = red[1]; int i0 = redi[0], i1 = redi[1];
    pred[b*TT + t] = (v1 > v0 || (v1 == v0 && i1 < i0)) ? i1 : i0;
  }
}

// ---------------- host ----------------
extern "C" void kernel_launch(void* const* d_in, const int* in_sizes, int n_in,
                              void* d_out, int out_size, void* d_ws, size_t ws_size,
                              hipStream_t stream){
  (void)in_sizes; (void)n_in; (void)out_size; (void)ws_size;
  const float* mol      = (const float*)d_in[1];
  const float* emb      = (const float*)d_in[2];
  const float* sa_in_w  = (const float*)d_in[3];
  const float* sa_in_b  = (const float*)d_in[4];
  const float* sa_out_w = (const float*)d_in[5];
  const float* sa_out_b = (const float*)d_in[6];
  const float* ca_in_w  = (const float*)d_in[7];
  const float* ca_in_b  = (const float*)d_in[8];
  const float* ca_out_w = (const float*)d_in[9];
  const float* ca_out_b = (const float*)d_in[10];
  const float* ff_w1    = (const float*)d_in[11];
  const float* ff_b1    = (const float*)d_in[12];
  const float* ff_w2    = (const float*)d_in[13];
  const float* ff_b2    = (const float*)d_in[14];
  const float* n1_g     = (const float*)d_in[15];
  const float* n1_b     = (const float*)d_in[16];
  const float* n2_g     = (const float*)d_in[17];
  const float* n2_b     = (const float*)d_in[18];
  const float* n3_g     = (const float*)d_in[19];
  const float* n3_b     = (const float*)d_in[20];
  const float* fn_g     = (const float*)d_in[21];
  const float* fn_b     = (const float*)d_in[22];
  const float* out_w1   = (const float*)d_in[23];
  const float* out_b1   = (const float*)d_in[24];
  const float* out_w2   = (const float*)d_in[25];
  const float* out_b2   = (const float*)d_in[26];
  const float* out_w3   = (const float*)d_in[27];
  const float* out_b3   = (const float*)d_in[28];

  int* pred = (int*)d_out;
  float* ws = (float*)d_ws;
  float* cosb   = ws;                     // 16384
  float* sinb   = cosb + 16384;           // 16384
  float* ca_tmp = sinb + 16384;           // 65536
  float* cac    = ca_tmp + 65536;         // 65536
  float* kc     = cac + 65536;            // 4194304
  float* vc     = kc + 4194304;           // 4194304
  float* x      = vc + 4194304;           // 16384
  float* qb     = x + 16384;              // 16384
  float* attn   = qb + 16384;             // 16384
  float* h1     = attn + 16384;           // 65536
  float* xf     = h1 + 65536;             // 16384
  float* hh1    = xf + 16384;             // 32768
  float* hh2    = hh1 + 32768;            // 32768

  k_tables<<<64, 256, 0, stream>>>(cosb, sinb);
  k_ca1<<<256, 256, 0, stream>>>(mol, ca_in_w, ca_in_b, ca_tmp);
  k_ca2<<<256, 256, 0, stream>>>(ca_tmp, ca_out_w, ca_out_b, cac);
  k_init<<<8, 256, 0, stream>>>(pred);

  for (int t = 1; t < TT; ++t){
    int p = t - 1;
    // key_t = fold_in(key(1), t) = threefry2x32([0,1], [0,t])
    uint32_t kk0, kk1;
    tf2x32(0u, 1u, 0u, (uint32_t)t, &kk0, &kk1);

    k_embed<<<64, 256, 0, stream>>>(pred, emb, cosb, sinb, x, p);
    for (int l = 0; l < LL; ++l){
      k_qkv<<<192, 256, 0, stream>>>(x, sa_in_w, sa_in_b, qb, kc, vc, l, p);
      k_attn<<<256, 64, 0, stream>>>(qb, kc, vc, pred, attn, l, p);
      k_oproj_ln<<<32, 512, 0, stream>>>(attn, sa_out_w, sa_out_b, cac,
                                         n1_g, n1_b, n2_g, n2_b, x, l);
      k_ff1<<<256, 256, 0, stream>>>(x, ff_w1, ff_b1, h1, l);
      k_ff2_ln<<<32, 512, 0, stream>>>(h1, ff_w2, ff_b2, n3_g, n3_b,
                                       fn_g, fn_b, x, xf, l, (l == LL-1) ? 1 : 0);
    }
    k_head<<<128, 256, 0, stream>>>(xf,  out_w1, out_b1, hh1, 1024, 512);
    k_head<<<128, 256, 0, stream>>>(hh1, out_w2, out_b2, hh2, 1024, 1024);
    k_sample<<<32, 128, 0, stream>>>(hh2, out_w3, out_b3, pred, t, kk0, kk1);
  }
}